// Round 15
// baseline (209.612 us; speedup 1.0000x reference)
//
#include <hip/hip_runtime.h>
#include <hip/hip_fp16.h>

// reaction_diffusion, 3-kernel pipeline (R26: both sides + epilogue fused —
// msg global roundtrip eliminated):
//   1. transpose: x[64,N] -> xth[N,64] fp16 (+ zero gcur)
//   2. partition: dual-side bucket multisplit, CH=4096 (exact R24 form;
//      R25 closed partition's book: fixed-cost-bound, bigger chunks win).
//   3. fused: ONE 512-thr block per (bucket, half) = 782 blocks. For side in
//      {0,1}: stage own run (9 int2 nt regs), zero fixed-cap dst, predicated
//      placement (csum straight into cold_s/colr_s), R20 dual-node oct-split
//      uint4 gather — but fragments land in padded LDS tiles [64][66] f16
//      (132B rows: gather writes 4x b32/lane conflict-free; epilogue column
//      reads 2-way = free) instead of global msg. Then in-block epilogue:
//      out[b,v] = tanh(colr*x - msgr + br) + (cold*x - msgd + bd) + x with
//      coalesced x reads / out writes. Eliminates 25.6MB msg roundtrip +
//      colsum roundtrip + final kernel launch. LDS 38.1KB -> 4 blk/CU.
// side 0 (dest = ei): w_main=wr -> msgr tile, w_col=wd -> cold
// side 1 (dest = ej): w_main=wd -> msgd tile, w_col=wr -> colr
// stage-1 payload int2: x=(bkt:9<<23)|(dl:7<<16)|(other:16), y=bf16(wm)<<16|bf16(wc)
// placed payload int: (bf16(wm)<<16)|other:16   -- requires N <= 65536
// NEVER per-edge global atomics (R15: 6.4M atomics = +230us).
// NEVER 64-node partition bins (R18) / CH=2048 (R25: +19us, fixed-cost x2).
// NEVER unconditional prefetch reorder (R21) / 1024-thr blocks (R22) /
// quad-node gather (R23). Dual-node is the measured MLP optimum.
// CAP=80 is a correctness bound: Poisson(32) P(deg>=80) ~ 1e-11.

#define BKT_SHIFT 7
#define BKT_NODES 128
#define HALF_NODES 64
#define RCAP 4608     // per-(side,bucket) run capacity: mean 4096, +8 sigma
#define CAP 80        // per-node fixed slot capacity (deg tail ~1e-11)
#define CH 4096       // partition chunk size (= 8 * 512 threads)
#define NBP 512       // padded per-side bin count (N <= 65536)
#define TP 66         // msg tile row pitch in halves (132B: odd dword stride)

__device__ __forceinline__ unsigned bf16_rne(float f) {
    unsigned u = __float_as_uint(f);
    unsigned rb = (u >> 16) & 1u;
    u += 0x7FFFu + rb;
    return u >> 16;
}
__device__ __forceinline__ float bf16_lo(int y) {
    return __uint_as_float(((unsigned)y) << 16);
}
__device__ __forceinline__ float bf16_hi(int y) {
    return __uint_as_float((unsigned)y & 0xFFFF0000u);
}

// kernel 1: x [64,N] -> xth [N,64] fp16; also zeroes gcur.
__global__ void transpose_kernel(const float* __restrict__ x, __half* __restrict__ xth,
                                 int* __restrict__ gcur, int ngcur, int N) {
    __shared__ float tile[64][65];
    int v0 = blockIdx.x * 64;
    int tx = threadIdx.x;   // 0..63
    int ty = threadIdx.y;   // 0..15
    int flat = blockIdx.x * 1024 + ty * 64 + tx;
    if (flat < ngcur) gcur[flat] = 0;
    if (v0 + tx < N) {
        for (int b = ty; b < 64; b += 16)
            tile[tx][b] = x[b * N + v0 + tx];
    }
    __syncthreads();
    for (int vl = ty; vl < 64; vl += 16) {
        int v = v0 + vl;
        if (v < N)
            xth[(size_t)v * 64 + tx] = __float2half(tile[vl][tx]);
    }
}

// kernel 2: dual-side chunked multi-split; edges in registers (read once).
// [exact R17/R24 form: 76KB LDS, 2 blocks/CU]
__global__ void __launch_bounds__(512) partition_kernel(
        const int* __restrict__ ei, const int* __restrict__ ej,
        const float* __restrict__ wr, const float* __restrict__ wd,
        int* __restrict__ gcur, int2* __restrict__ runs,
        int E, int NB) {
    __shared__ int cnt[2 * NBP];     // 4 KB
    __shared__ int base_a[2 * NBP];  // 4 KB
    __shared__ int gb[2 * NBP];      // 4 KB
    __shared__ int2 buf[2 * CH];     // 64 KB

    int tid = threadIdx.x;
    int e0 = blockIdx.x * CH;
    int ch_len = min(CH, E - e0);
    if (ch_len <= 0) return;

    int my_i[8], my_j[8];
    unsigned my_w[8];
    #pragma unroll
    for (int k = 0; k < 8; ++k) {
        int t = tid + k * 512;
        if (t < ch_len) {
            int e = e0 + t;
            my_i[k] = ei[e];
            my_j[k] = ej[e];
            my_w[k] = (bf16_rne(wr[e]) << 16) | bf16_rne(wd[e]);
        } else {
            my_i[k] = -1;
        }
    }

    for (int b = tid; b < 2 * NBP; b += 512) cnt[b] = 0;
    __syncthreads();
    #pragma unroll
    for (int k = 0; k < 8; ++k) {
        if (my_i[k] >= 0) {
            atomicAdd(&cnt[my_i[k] >> BKT_SHIFT], 1);
            atomicAdd(&cnt[NBP + (my_j[k] >> BKT_SHIFT)], 1);
        }
    }
    __syncthreads();
    if (tid < 64) {
        int carry = 0;
        #pragma unroll
        for (int c = 0; c < (2 * NBP) / 64; ++c) {
            int idx = c * 64 + tid;
            int val = cnt[idx];
            int scan = val;
            for (int off = 1; off < 64; off <<= 1) {
                int n = __shfl_up(scan, off, 64);
                if (tid >= off) scan += n;
            }
            int excl = scan - val + carry;
            base_a[idx] = excl;
            cnt[idx] = excl;            // becomes cursor
            carry += __shfl(scan, 63, 64);
        }
    }
    __syncthreads();
    #pragma unroll
    for (int k = 0; k < 8; ++k) {
        if (my_i[k] >= 0) {
            int i = my_i[k], j = my_j[k];
            unsigned wv = my_w[k];
            int b0 = i >> BKT_SHIFT;
            int p0 = atomicAdd(&cnt[b0], 1);
            buf[p0] = make_int2((int)(((unsigned)b0 << 23) | ((unsigned)(i & 127) << 16) | (unsigned)j),
                                (int)wv);
            int b1 = j >> BKT_SHIFT;
            int p1 = atomicAdd(&cnt[NBP + b1], 1);
            buf[p1] = make_int2((int)(((unsigned)b1 << 23) | ((unsigned)(j & 127) << 16) | (unsigned)i),
                                (int)((wv << 16) | (wv >> 16)));
        }
    }
    __syncthreads();
    for (int cb = tid; cb < 2 * NBP; cb += 512) {
        int n = cnt[cb] - base_a[cb];
        if (n > 0) {
            int side = cb >> 9;
            int bkt = cb & (NBP - 1);
            gb[cb] = atomicAdd(&gcur[side * NB + bkt], n);
        }
    }
    __syncthreads();
    int total = 2 * ch_len;
    for (int t = tid; t < total; t += 512) {
        int2 p = buf[t];
        int side = (t >= ch_len) ? 1 : 0;
        int bkt = ((unsigned)p.x >> 23) & 0x1FF;
        int cb = side * NBP + bkt;
        int rank = gb[cb] + (t - base_a[cb]);
        if (rank < RCAP)
            runs[((size_t)(side * NB + bkt)) * RCAP + rank] = p;
    }
}

// accumulate one payload into accumulator set S (weight hi16 of P, uint4 D)
#define ACC8S(S0,S1,S2,S3,S4,S5,S6,S7, P, D)                              \
    {                                                                     \
        float wv_ = bf16_hi(P);                                           \
        float2 f_;                                                        \
        f_ = __half22float2(*(const __half2*)&(D).x);                     \
        S0 = fmaf(wv_, f_.x, S0); S1 = fmaf(wv_, f_.y, S1);               \
        f_ = __half22float2(*(const __half2*)&(D).y);                     \
        S2 = fmaf(wv_, f_.x, S2); S3 = fmaf(wv_, f_.y, S3);               \
        f_ = __half22float2(*(const __half2*)&(D).z);                     \
        S4 = fmaf(wv_, f_.x, S4); S5 = fmaf(wv_, f_.y, S5);               \
        f_ = __half22float2(*(const __half2*)&(D).w);                     \
        S6 = fmaf(wv_, f_.x, S6); S7 = fmaf(wv_, f_.y, S7);               \
    }

#define COMB3(A) { A += __shfl_xor(A, 8); A += __shfl_xor(A, 16); A += __shfl_xor(A, 32); }

// write 8 batches (4 half2 words) for one node into a padded LDS tile row.
// lane l writes dwords 4l..4l+3 of row dll (132B rows -> banks 4l+k spread).
#define TILE8(TILE, DLL, S0,S1,S2,S3,S4,S5,S6,S7)                         \
    {                                                                     \
        __half2 h0 = __floats2half2_rn(S0, S1);                           \
        __half2 h1 = __floats2half2_rn(S2, S3);                           \
        __half2 h2 = __floats2half2_rn(S4, S5);                           \
        __half2 h3 = __floats2half2_rn(S6, S7);                           \
        unsigned* row_ = (unsigned*)&TILE[DLL][0];                        \
        row_[4 * lane + 0] = *(unsigned*)&h0;                             \
        row_[4 * lane + 1] = *(unsigned*)&h1;                             \
        row_[4 * lane + 2] = *(unsigned*)&h2;                             \
        row_[4 * lane + 3] = *(unsigned*)&h3;                             \
    }

// kernel 3: fused dual-side sortgather + epilogue. One 512-thr block per
// (bucket, half); 38.1 KB LDS -> 4 blk/CU.
__global__ void __launch_bounds__(512, 8) fused_kernel(
        const int* __restrict__ gcur, const int2* __restrict__ runs,
        const __half* __restrict__ xth, const float* __restrict__ x,
        const float* __restrict__ br, const float* __restrict__ bd,
        float* __restrict__ out, int NB, int N) {
    __shared__ int cur[HALF_NODES];
    __shared__ float cold_s[HALF_NODES];           // side 0 csum (sum wd, ei=v)
    __shared__ float colr_s[HALF_NODES];           // side 1 csum (sum wr, ej=v)
    __shared__ int dst[HALF_NODES * CAP];          // 20 KB fixed-cap payloads
    __shared__ unsigned short tmr[HALF_NODES][TP]; // msgr tile, 8.25 KB
    __shared__ unsigned short tmd[HALF_NODES][TP]; // msgd tile, 8.25 KB

    int blk = blockIdx.x;
    int bucket = blk >> 1;
    int h = blk & 1;
    int v0 = (bucket << BKT_SHIFT) + h * HALF_NODES;
    int tid = threadIdx.x;
    int lane = tid & 63;
    int g  = lane >> 3;                 // payload slot within oct (0..7)
    int bl = lane & 7;                  // 16B chunk: batches 8*bl..8*bl+7
    int wid = tid >> 6;
    const uint4* __restrict__ xq = (const uint4*)xth;   // [N][8] uint4 rows

    if (tid < HALF_NODES) { cold_s[tid] = 0.f; colr_s[tid] = 0.f; }

    #pragma unroll
    for (int side = 0; side < 2; ++side) {
        int sb = side * NB + bucket;
        int len = min(gcur[sb], RCAP);
        size_t roff = (size_t)sb * RCAP;

        // stage this side's full run: 9 int2 regs (nt). Valid payloads never
        // have x == -1 (bkt field <= 390 < 511).
        int2 my[9];
        #pragma unroll
        for (int k = 0; k < 9; ++k) {
            int t = tid + k * 512;
            if (t < len) {
                long long raw = __builtin_nontemporal_load((const long long*)(runs + roff + t));
                my[k].x = (int)(unsigned)(raw & 0xFFFFFFFFll);
                my[k].y = (int)(unsigned)((unsigned long long)raw >> 32);
            } else my[k].x = -1;
        }

        // zero cur + dst (pads/over-reads see w=0, other=0)
        if (tid < HALF_NODES) cur[tid] = 0;
        {
            int4* d4 = (int4*)dst;
            for (int idx = tid; idx < (HALF_NODES * CAP) / 4; idx += 512)
                d4[idx] = make_int4(0, 0, 0, 0);
        }
        __syncthreads();
        // placement: predicated on ownership (dl's half == h).
        float* cs = side ? colr_s : cold_s;
        #pragma unroll
        for (int k = 0; k < 9; ++k) {
            if (my[k].x != -1) {
                int dl = ((unsigned)my[k].x >> 16) & 0x7F;
                if ((dl >> 6) == h) {
                    int dll = dl & (HALF_NODES - 1);
                    int pos = atomicAdd(&cur[dll], 1);
                    if (pos < CAP)
                        dst[dll * CAP + pos] =
                            (int)(((unsigned)my[k].y & 0xFFFF0000u) | ((unsigned)my[k].x & 0xFFFFu));
                    atomicAdd(&cs[dll], bf16_lo(my[k].y));
                }
            }
        }
        __syncthreads();

        // gather (exact R20 dual-node form), fragments -> LDS tile.
        for (int t = 0; t < HALF_NODES / 8; t += 2) {
            int dllA = wid * (HALF_NODES / 8) + t;
            int dllB = dllA + 1;
            const int* payA = dst + dllA * CAP + g;
            const int* payB = dst + dllB * CAP + g;
            int noctA = (min(cur[dllA], CAP) + 7) >> 3;
            int noctB = (min(cur[dllB], CAP) + 7) >> 3;
            int noct = max(noctA, noctB);               // <= CAP/8 = 10
            float a0 = 0.f, a1 = 0.f, a2 = 0.f, a3 = 0.f;
            float a4 = 0.f, a5 = 0.f, a6 = 0.f, a7 = 0.f;
            float c0 = 0.f, c1 = 0.f, c2 = 0.f, c3 = 0.f;
            float c4 = 0.f, c5 = 0.f, c6 = 0.f, c7 = 0.f;
            int o = 0;
            for (; o + 2 <= noct; o += 2) {
                int pA0 = payA[8 * o];
                int pA1 = payA[8 * o + 8];
                int pB0 = payB[8 * o];
                int pB1 = payB[8 * o + 8];
                uint4 dA0 = xq[(((size_t)((unsigned)pA0 & 0xFFFFu)) << 3) + bl];
                uint4 dA1 = xq[(((size_t)((unsigned)pA1 & 0xFFFFu)) << 3) + bl];
                uint4 dB0 = xq[(((size_t)((unsigned)pB0 & 0xFFFFu)) << 3) + bl];
                uint4 dB1 = xq[(((size_t)((unsigned)pB1 & 0xFFFFu)) << 3) + bl];
                ACC8S(a0,a1,a2,a3,a4,a5,a6,a7, pA0, dA0)
                ACC8S(a0,a1,a2,a3,a4,a5,a6,a7, pA1, dA1)
                ACC8S(c0,c1,c2,c3,c4,c5,c6,c7, pB0, dB0)
                ACC8S(c0,c1,c2,c3,c4,c5,c6,c7, pB1, dB1)
            }
            if (o < noct) {
                int pA0 = payA[8 * o];
                int pB0 = payB[8 * o];
                uint4 dA0 = xq[(((size_t)((unsigned)pA0 & 0xFFFFu)) << 3) + bl];
                uint4 dB0 = xq[(((size_t)((unsigned)pB0 & 0xFFFFu)) << 3) + bl];
                ACC8S(a0,a1,a2,a3,a4,a5,a6,a7, pA0, dA0)
                ACC8S(c0,c1,c2,c3,c4,c5,c6,c7, pB0, dB0)
            }
            COMB3(a0) COMB3(a1) COMB3(a2) COMB3(a3)
            COMB3(a4) COMB3(a5) COMB3(a6) COMB3(a7)
            COMB3(c0) COMB3(c1) COMB3(c2) COMB3(c3)
            COMB3(c4) COMB3(c5) COMB3(c6) COMB3(c7)
            if (lane < 8) {
                if (side == 0) {
                    TILE8(tmr, dllA, a0,a1,a2,a3,a4,a5,a6,a7)
                    TILE8(tmr, dllB, c0,c1,c2,c3,c4,c5,c6,c7)
                } else {
                    TILE8(tmd, dllA, a0,a1,a2,a3,a4,a5,a6,a7)
                    TILE8(tmd, dllB, c0,c1,c2,c3,c4,c5,c6,c7)
                }
            }
        }
        __syncthreads();    // tiles complete / dst reusable by next side
    }

    // epilogue: thread (tx=lane, ty=wid 0..7) handles node v0+tx, batches
    // ty, ty+8, ... Tile column reads at 132B row stride -> 2-way (free);
    // x reads / out writes coalesced along tx.
    int tx = lane;
    int v = v0 + tx;
    if (v < N) {
        float colr = colr_s[tx];
        float cold = cold_s[tx];
        float brv = br[v], bdv = bd[v];
        const __half* rr = (const __half*)&tmr[tx][0];
        const __half* rd = (const __half*)&tmd[tx][0];
        for (int b = wid; b < 64; b += 8) {
            float xv = x[(size_t)b * N + v];
            float mr = __half2float(rr[b]);
            float md = __half2float(rd[b]);
            float r2 = colr * xv - mr + brv;
            float d2 = cold * xv - md + bdv;
            out[(size_t)b * N + v] = tanhf(r2) + d2 + xv;
        }
    }
}

extern "C" void kernel_launch(void* const* d_in, const int* in_sizes, int n_in,
                              void* d_out, int out_size, void* d_ws, size_t ws_size,
                              hipStream_t stream) {
    const float* x  = (const float*)d_in[1];
    const int*   ei = (const int*)d_in[2];
    const int*   ej = (const int*)d_in[3];
    const float* wr = (const float*)d_in[4];
    const float* wd = (const float*)d_in[5];
    const float* br = (const float*)d_in[6];
    const float* bd = (const float*)d_in[7];
    float* out = (float*)d_out;

    int E = in_sizes[2];
    int N = in_sizes[6];
    int NB = (N + BKT_NODES - 1) >> BKT_SHIFT;
    (void)out_size; (void)ws_size; (void)n_in;

    // workspace: xth[N*64 f16] | gcur[2NB] | runs[2*NB*RCAP int2]  (~35 MB)
    char* w = (char*)d_ws;
    __half* xth = (__half*)w;    w += (size_t)N * 64 * 2;
    int* gcur   = (int*)w;       w += (size_t)2 * NB * 4;
    w = (char*)(((uintptr_t)w + 15) & ~(uintptr_t)15);
    int2* runs  = (int2*)w;

    dim3 tb(64, 16);
    int ntiles = (N + 63) / 64;
    transpose_kernel<<<ntiles, tb, 0, stream>>>(x, xth, gcur, 2 * NB, N);

    int nchunks = (E + CH - 1) / CH;
    partition_kernel<<<nchunks, 512, 0, stream>>>(ei, ej, wr, wd, gcur, runs, E, NB);

    fused_kernel<<<2 * NB, 512, 0, stream>>>(gcur, runs, xth, x, br, bd, out, NB, N);
}